// Round 1
// baseline (29298.358 us; speedup 1.0000x reference)
//
#include <hip/hip_runtime.h>
#include <cstddef>

#define NB 32
#define NT 2048
#define ND 256
#define NH 256
#define NG 1024   // 4*H
#define ROWS 16   // bt-rows per block in zx_kernel

__device__ __forceinline__ float sigf(float x) {
    return 1.0f / (1.0f + __expf(-x));
}
__device__ __forceinline__ float tanh_fast(float x) {
    // tanh(x) = 2*sigmoid(2x) - 1 ; saturates correctly for large |x|
    return 2.0f / (1.0f + __expf(-2.0f * x)) - 1.0f;
}

// Phase 1: ZX[bt][j] = sum_k X[bt][k] * Wi[k][j] + bias[j]
// grid: (B*T/ROWS) blocks x 256 threads; each thread: 4 cols x ROWS rows.
__global__ __launch_bounds__(256) void zx_kernel(const float* __restrict__ X,
                                                 const float* __restrict__ Wi,
                                                 const float* __restrict__ bias,
                                                 float* __restrict__ ZX) {
    __shared__ float xs[ROWS][ND];   // 16 KB
    const int tid = threadIdx.x;
    const size_t row0 = (size_t)blockIdx.x * ROWS;

    // stage 16 input rows (ROWS*ND = 4096 floats) via float4, coalesced
    const float4* Xv = (const float4*)(X + row0 * ND);
    float4* xsv = (float4*)(&xs[0][0]);
#pragma unroll
    for (int i = 0; i < (ROWS * ND / 4) / 256; ++i)
        xsv[tid + i * 256] = Xv[tid + i * 256];
    __syncthreads();

    const int j0 = tid * 4;
    const float4 bv = *(const float4*)(bias + j0);
    float acc[ROWS][4];
#pragma unroll
    for (int r = 0; r < ROWS; ++r) {
        acc[r][0] = bv.x; acc[r][1] = bv.y; acc[r][2] = bv.z; acc[r][3] = bv.w;
    }

    for (int k = 0; k < ND; ++k) {
        const float4 w = *(const float4*)(Wi + (size_t)k * NG + j0);
#pragma unroll
        for (int r = 0; r < ROWS; ++r) {
            const float x = xs[r][k];
            acc[r][0] = fmaf(x, w.x, acc[r][0]);
            acc[r][1] = fmaf(x, w.y, acc[r][1]);
            acc[r][2] = fmaf(x, w.z, acc[r][2]);
            acc[r][3] = fmaf(x, w.w, acc[r][3]);
        }
    }

#pragma unroll
    for (int r = 0; r < ROWS; ++r) {
        float4 o;
        o.x = acc[r][0]; o.y = acc[r][1]; o.z = acc[r][2]; o.w = acc[r][3];
        *(float4*)(ZX + (row0 + r) * NG + j0) = o;
    }
}

// Phase 2: sequential recurrence, one block per batch.
// 512 threads; thread handles gate columns {2*tid, 2*tid+1}.
__global__ __launch_bounds__(512) void rec_kernel(
    const float* __restrict__ ZX,
    const float* __restrict__ X,
    const float* __restrict__ Wi,
    const float* __restrict__ Wh,
    const float* __restrict__ bias,
    const int* __restrict__ lengths,
    float* __restrict__ out,
    const int use_zx)
{
    __shared__ float hs[NH];   // current hidden state
    __shared__ float zs[NG];   // pre-activations for this step
    __shared__ float xs[ND];   // staged x_t (fallback path only)

    const int b   = blockIdx.x;
    const int tid = threadIdx.x;
    const int c0  = tid * 2;

    const int len   = lengths[b];
    const int steps = (len < 1) ? 1 : len;   // idx = max(0, len-1); run idx+1 steps

    float c_state = 0.0f;                    // cell state for hidden unit `tid` (tid < NH)
    if (tid < NH) hs[tid] = 0.0f;

    float b0 = 0.0f, b1 = 0.0f;
    if (!use_zx) { b0 = bias[c0]; b1 = bias[c0 + 1]; }
    __syncthreads();

    for (int t = 0; t < steps; ++t) {
        float a0, a1;
        if (use_zx) {
            const float2 z2 = *(const float2*)(ZX + ((size_t)b * NT + t) * NG + c0);
            a0 = z2.x; a1 = z2.y;
        } else {
            a0 = b0; a1 = b1;
            if (tid < ND) xs[tid] = X[((size_t)b * NT + t) * ND + tid];
            __syncthreads();
#pragma unroll 2
            for (int k = 0; k < ND; k += 4) {
                const float4 xv = *(const float4*)(xs + k);
                const float2 w0 = *(const float2*)(Wi + (size_t)(k + 0) * NG + c0);
                const float2 w1 = *(const float2*)(Wi + (size_t)(k + 1) * NG + c0);
                const float2 w2 = *(const float2*)(Wi + (size_t)(k + 2) * NG + c0);
                const float2 w3 = *(const float2*)(Wi + (size_t)(k + 3) * NG + c0);
                a0 = fmaf(xv.x, w0.x, a0); a1 = fmaf(xv.x, w0.y, a1);
                a0 = fmaf(xv.y, w1.x, a0); a1 = fmaf(xv.y, w1.y, a1);
                a0 = fmaf(xv.z, w2.x, a0); a1 = fmaf(xv.z, w2.y, a1);
                a0 = fmaf(xv.w, w3.x, a0); a1 = fmaf(xv.w, w3.y, a1);
            }
        }

        // h @ Wh : each thread dots hs[0:256] against two Wh columns
#pragma unroll 2
        for (int k = 0; k < NH; k += 4) {
            const float4 hv = *(const float4*)(hs + k);
            const float2 w0 = *(const float2*)(Wh + (size_t)(k + 0) * NG + c0);
            const float2 w1 = *(const float2*)(Wh + (size_t)(k + 1) * NG + c0);
            const float2 w2 = *(const float2*)(Wh + (size_t)(k + 2) * NG + c0);
            const float2 w3 = *(const float2*)(Wh + (size_t)(k + 3) * NG + c0);
            a0 = fmaf(hv.x, w0.x, a0); a1 = fmaf(hv.x, w0.y, a1);
            a0 = fmaf(hv.y, w1.x, a0); a1 = fmaf(hv.y, w1.y, a1);
            a0 = fmaf(hv.z, w2.x, a0); a1 = fmaf(hv.z, w2.y, a1);
            a0 = fmaf(hv.w, w3.x, a0); a1 = fmaf(hv.w, w3.y, a1);
        }

        float2 zout; zout.x = a0; zout.y = a1;
        *(float2*)(zs + c0) = zout;
        __syncthreads();

        if (tid < NH) {
            const float iv = zs[tid];
            const float fv = zs[NH + tid];
            const float gv = zs[2 * NH + tid];
            const float ov = zs[3 * NH + tid];
            c_state = sigf(fv) * c_state + sigf(iv) * tanh_fast(gv);
            hs[tid] = sigf(ov) * tanh_fast(c_state);
        }
        __syncthreads();
    }

    if (tid < NH) out[(size_t)b * NH + tid] = hs[tid];
}

extern "C" void kernel_launch(void* const* d_in, const int* in_sizes, int n_in,
                              void* d_out, int out_size, void* d_ws, size_t ws_size,
                              hipStream_t stream) {
    const float* X       = (const float*)d_in[0];
    const int*   lengths = (const int*)d_in[1];
    const float* Wi      = (const float*)d_in[2];
    const float* Wh      = (const float*)d_in[3];
    const float* bias    = (const float*)d_in[4];
    float* out = (float*)d_out;

    const size_t zx_bytes = (size_t)NB * NT * NG * sizeof(float);  // 256 MB
    const int use_zx = (ws_size >= zx_bytes) ? 1 : 0;
    float* ZX = (float*)d_ws;

    if (use_zx) {
        zx_kernel<<<dim3((NB * NT) / ROWS), dim3(256), 0, stream>>>(X, Wi, bias, ZX);
    }
    rec_kernel<<<dim3(NB), dim3(512), 0, stream>>>(ZX, X, Wi, Wh, bias, lengths, out, use_zx);
}